// Round 1
// baseline (411.614 us; speedup 1.0000x reference)
//
#include <hip/hip_runtime.h>

#define H_ 128
#define W_ 128
#define B_ 4
#define NPIX (B_*H_*W_)   // 65536
#define BN_EPS 1e-3f

// ---------------------------------------------------------------------------
// Kernel 1: xi = x @ Wi + bi      [65536,256] = [65536,256] x [256,256]
// block = 256 threads, 32 pixels x 256 channels; thread tile = 4 px x 8 f.
// f-set per thread: {4t..4t+3} u {128+4t..128+4t+3} so LDS/global accesses are
// lane-contiguous float4 (conflict-free b128 pattern).
// ---------------------------------------------------------------------------
__global__ __launch_bounds__(256, 4) void k_xi(
    const float* __restrict__ x, const float* __restrict__ Wi,
    const float* __restrict__ bi, float* __restrict__ xi)
{
    __shared__ float xs[32 * 256];   // 32 KB
    const int tid = threadIdx.x;
    const long long p0 = (long long)blockIdx.x * 32;

    // stage x rows (contiguous, coalesced float4)
    const float* xsrc = x + p0 * 256;
    for (int i = tid * 4; i < 32 * 256; i += 1024)
        *(float4*)&xs[i] = *(const float4*)&xsrc[i];
    __syncthreads();

    const int ft = tid & 31;   // 0..31
    const int pg = tid >> 5;   // 0..7  -> pixels pg*4 .. pg*4+3
    const int f0 = 4 * ft;
    const int f1 = 128 + 4 * ft;

    float acc[4][8];
#pragma unroll
    for (int a = 0; a < 4; ++a)
#pragma unroll
        for (int b = 0; b < 8; ++b) acc[a][b] = 0.f;

    for (int c4 = 0; c4 < 256; c4 += 4) {
        float4 xv[4];
#pragma unroll
        for (int pp = 0; pp < 4; ++pp)
            xv[pp] = *(const float4*)&xs[(pg * 4 + pp) * 256 + c4];
#pragma unroll
        for (int j = 0; j < 4; ++j) {
            float4 w0 = *(const float4*)&Wi[(c4 + j) * 256 + f0];
            float4 w1 = *(const float4*)&Wi[(c4 + j) * 256 + f1];
#pragma unroll
            for (int pp = 0; pp < 4; ++pp) {
                float xvj = ((const float*)&xv[pp])[j];
                acc[pp][0] += xvj * w0.x; acc[pp][1] += xvj * w0.y;
                acc[pp][2] += xvj * w0.z; acc[pp][3] += xvj * w0.w;
                acc[pp][4] += xvj * w1.x; acc[pp][5] += xvj * w1.y;
                acc[pp][6] += xvj * w1.z; acc[pp][7] += xvj * w1.w;
            }
        }
    }

    float4 b0 = *(const float4*)&bi[f0];
    float4 b1 = *(const float4*)&bi[f1];
#pragma unroll
    for (int pp = 0; pp < 4; ++pp) {
        long long row = (p0 + pg * 4 + pp) * 256;
        float4 o0 = { acc[pp][0] + b0.x, acc[pp][1] + b0.y,
                      acc[pp][2] + b0.z, acc[pp][3] + b0.w };
        float4 o1 = { acc[pp][4] + b1.x, acc[pp][5] + b1.y,
                      acc[pp][6] + b1.z, acc[pp][7] + b1.w };
        *(float4*)&xi[row + f0] = o0;
        *(float4*)&xi[row + f1] = o1;
    }
}

// ---------------------------------------------------------------------------
// Kernel 2: fused r -> w -> involution gather.  16 pixels (one row segment)
// per block, 256 threads.
// LDS plan (floats), regions aliased across phases:
//   [0,13888)            phase A/B/C: xs2[16][256] at 0, Wst[144][68] at 4096
//   [0,13824)            phase D:     xin[3][18][256]  (overwrites the above)
//   [13888,14976)        rs[16][68]   (pad 68 -> 2-way bank free)
//   [14976,17280)        wlds[16][144]
// total 17280 floats = 69.1 KB -> 2 blocks/CU
// ---------------------------------------------------------------------------
#define SM_TOTAL 17280
#define OFF_WST 4096
#define WST_STRIDE 68
#define OFF_RS 13888
#define RS_STRIDE 68
#define OFF_WL 14976

__global__ __launch_bounds__(256, 2) void k_inv(
    const float* __restrict__ x,
    const float* __restrict__ Wr, const float* __restrict__ br,
    const float* __restrict__ gamma, const float* __restrict__ beta,
    const float* __restrict__ mean, const float* __restrict__ var,
    const float* __restrict__ Ws, const float* __restrict__ bs,
    const float* __restrict__ xi, float* __restrict__ out)
{
    __shared__ float sm[SM_TOTAL];
    const int tid = threadIdx.x;
    const int p0 = blockIdx.x * 16;   // W=128 divisible by 16 -> row-aligned
    const int b  = p0 >> 14;
    const int hw = p0 & 16383;
    const int h  = hw >> 7;
    const int w0 = hw & 127;

    // ---- phase A: stage x tile + transposed Ws ----
    {
        const float* xsrc = x + (long long)p0 * 256;
        for (int i = tid * 4; i < 4096; i += 1024)
            *(float4*)&sm[i] = *(const float4*)&xsrc[i];
        for (int t = tid; t < 64 * 144; t += 256) {
            int d = t / 144, k = t - d * 144;
            sm[OFF_WST + k * WST_STRIDE + d] = Ws[t];
        }
    }
    __syncthreads();

    // ---- phase B: r[p][d] = relu(BN(x@Wr + br)) ----
    {
        const int d  = tid & 63;
        const int pg = tid >> 6;   // 0..3 -> pixels pg*4..+3
        const float br_d = br[d];
        const float mean_d = mean[d];
        const float sc = gamma[d] * rsqrtf(var[d] + BN_EPS);
        const float beta_d = beta[d];
        float a0 = 0, a1 = 0, a2 = 0, a3 = 0;
        for (int c4 = 0; c4 < 256; c4 += 4) {
            float4 x0 = *(const float4*)&sm[(pg * 4 + 0) * 256 + c4];
            float4 x1 = *(const float4*)&sm[(pg * 4 + 1) * 256 + c4];
            float4 x2 = *(const float4*)&sm[(pg * 4 + 2) * 256 + c4];
            float4 x3 = *(const float4*)&sm[(pg * 4 + 3) * 256 + c4];
#pragma unroll
            for (int j = 0; j < 4; ++j) {
                float wr = Wr[(c4 + j) * 64 + d];
                a0 += ((const float*)&x0)[j] * wr;
                a1 += ((const float*)&x1)[j] * wr;
                a2 += ((const float*)&x2)[j] * wr;
                a3 += ((const float*)&x3)[j] * wr;
            }
        }
        sm[OFF_RS + (pg * 4 + 0) * RS_STRIDE + d] = fmaxf((a0 + br_d - mean_d) * sc + beta_d, 0.f);
        sm[OFF_RS + (pg * 4 + 1) * RS_STRIDE + d] = fmaxf((a1 + br_d - mean_d) * sc + beta_d, 0.f);
        sm[OFF_RS + (pg * 4 + 2) * RS_STRIDE + d] = fmaxf((a2 + br_d - mean_d) * sc + beta_d, 0.f);
        sm[OFF_RS + (pg * 4 + 3) * RS_STRIDE + d] = fmaxf((a3 + br_d - mean_d) * sc + beta_d, 0.f);
    }
    __syncthreads();

    // ---- phase C: wlds[p][k] = r[p][:] @ Ws[:,k] + bs[k] ----
    {
        const int p  = tid & 15;
        const int kg = tid >> 4;   // k = kg*9 + j
        float acc9[9];
#pragma unroll
        for (int j = 0; j < 9; ++j) acc9[j] = bs[kg * 9 + j];
        for (int d4 = 0; d4 < 64; d4 += 4) {
            float4 rv = *(const float4*)&sm[OFF_RS + p * RS_STRIDE + d4];
#pragma unroll
            for (int j = 0; j < 9; ++j) {
                float4 wv = *(const float4*)&sm[OFF_WST + (kg * 9 + j) * WST_STRIDE + d4];
                acc9[j] += rv.x * wv.x + rv.y * wv.y + rv.z * wv.z + rv.w * wv.w;
            }
        }
#pragma unroll
        for (int j = 0; j < 9; ++j)
            sm[OFF_WL + p * 144 + kg * 9 + j] = acc9[j];
    }
    __syncthreads();   // wlds written; region A reads done -> safe to overwrite

    // ---- phase D part 1: stage xi halo xin[3][18][256] with zero fill ----
    {
        for (int t = tid; t < 3 * 18 * 64; t += 256) {   // float4 granules
            int row = t / (18 * 64);
            int rem = t - row * (18 * 64);
            int col = rem >> 6;
            int cq  = rem & 63;
            int sh = h + row - 1;
            int sw = w0 + col - 1;
            float4 v = { 0.f, 0.f, 0.f, 0.f };
            if ((unsigned)sh < 128u && (unsigned)sw < 128u) {
                long long src = ((long long)((b * 128 + sh) * 128 + sw)) * 256 + cq * 4;
                v = *(const float4*)&xi[src];
            }
            *(float4*)&sm[t * 4] = v;
        }
    }
    __syncthreads();

    // ---- phase D part 2: gather.  thread = output channel co. ----
    {
        const int co = tid;
        const int g  = co >> 4;
        const int f2 = co & 15;
        // precompute the 9 (kpos,c) decodes: idx = g*144 + f2*9 + kk
        int aoff[9];   // LDS float offset base (add p*256)
        int coff[9];
#pragma unroll
        for (int kk = 0; kk < 9; ++kk) {
            int idx  = g * 144 + f2 * 9 + kk;
            int kpos = idx >> 8;
            int c    = idx & 255;
            int ki   = kpos / 3;
            int kj   = kpos - ki * 3;
            aoff[kk] = (ki * 18 + kj) * 256 + c;   // + p*256 for pixel p
            coff[kk] = g * 9 + kk;                 // wlds column
        }
#pragma unroll 4
        for (int p = 0; p < 16; ++p) {
            float a = 0.f;
#pragma unroll
            for (int kk = 0; kk < 9; ++kk) {
                float wv = sm[OFF_WL + p * 144 + coff[kk]];
                float xv = sm[aoff[kk] + p * 256];
                a += wv * xv;
            }
            out[(long long)(p0 + p) * 256 + co] = a;
        }
    }
}

extern "C" void kernel_launch(void* const* d_in, const int* in_sizes, int n_in,
                              void* d_out, int out_size, void* d_ws, size_t ws_size,
                              hipStream_t stream) {
    const float* x     = (const float*)d_in[0];
    const float* Wr    = (const float*)d_in[1];
    const float* br    = (const float*)d_in[2];
    const float* gamma = (const float*)d_in[3];
    const float* beta  = (const float*)d_in[4];
    const float* mean  = (const float*)d_in[5];
    const float* var   = (const float*)d_in[6];
    const float* Ws    = (const float*)d_in[7];
    const float* bs    = (const float*)d_in[8];
    const float* Wi    = (const float*)d_in[9];
    const float* bi    = (const float*)d_in[10];
    float* out = (float*)d_out;
    float* xi  = (float*)d_ws;   // 65536*256 floats = 67.1 MB

    k_xi<<<dim3(NPIX / 32), dim3(256), 0, stream>>>(x, Wi, bi, xi);
    k_inv<<<dim3(NPIX / 16), dim3(256), 0, stream>>>(
        x, Wr, br, gamma, beta, mean, var, Ws, bs, xi, out);
}

// Round 2
// 206.616 us; speedup vs baseline: 1.9922x; 1.9922x over previous
//
#include <hip/hip_runtime.h>

#define NPIX 65536
#define BN_EPS 1e-3f

typedef __attribute__((ext_vector_type(8))) short bf16x8;
typedef __attribute__((ext_vector_type(4))) float f32x4;

__device__ inline unsigned short f2b(float f) {
    unsigned int u = __float_as_uint(f);
    unsigned int r = (u + 0x7fffu + ((u >> 16) & 1u)) >> 16;
    return (unsigned short)r;
}
__device__ inline float b2f(unsigned short h) {
    return __uint_as_float(((unsigned int)h) << 16);
}

// ---------------------------------------------------------------------------
// k_prep: Bt[n][k] = bf16 of (n<256 ? Wi[k][n] : Wr[k][n-256])   [320,256]
//         Wst[n][k] = bf16 of Ws[k][n]                            [144,64]
// ---------------------------------------------------------------------------
__global__ void k_prep(const float* __restrict__ Wi, const float* __restrict__ Wr,
                       const float* __restrict__ Ws,
                       unsigned short* __restrict__ Bt, unsigned short* __restrict__ Wst) {
    int t = blockIdx.x * 256 + threadIdx.x;
    if (t < 320 * 256) {
        int n = t >> 8, k = t & 255;
        float v = (n < 256) ? Wi[k * 256 + n] : Wr[k * 64 + (n - 256)];
        Bt[t] = f2b(v);
    } else {
        int t2 = t - 320 * 256;
        if (t2 < 144 * 64) {
            int n = t2 >> 6, k = t2 & 63;
            Wst[t2] = f2b(Ws[k * 144 + n]);
        }
    }
}

// ---------------------------------------------------------------------------
// k1: MFMA GEMM  [65536,320] = x[65536,256] @ Bt^T, fused epilogues:
//     n<256  -> xi_b = bf16(acc + bi[n])
//     n>=256 -> r_b  = bf16(relu(BN(acc + br)))
// block = 256 thr (4 waves), M-tile 64 px, wave w covers n-tiles w*5..w*5+4.
// ---------------------------------------------------------------------------
#define APAD 264   // 256 + 8 bf16 pad -> 2-way (free) b128 bank pattern
__global__ __launch_bounds__(256, 3) void k1_gemm(
    const float* __restrict__ x, const unsigned short* __restrict__ Bt,
    const float* __restrict__ bi, const float* __restrict__ br,
    const float* __restrict__ gamma, const float* __restrict__ beta,
    const float* __restrict__ mean, const float* __restrict__ var,
    unsigned short* __restrict__ xi_b, unsigned short* __restrict__ r_b)
{
    __shared__ unsigned short As[64 * APAD];   // 33.8 KB
    const int tid = threadIdx.x;
    const int p0 = blockIdx.x * 64;

    // stage A: 64 rows x 256 ch, fp32 -> bf16
    {
        const float* xs = x + (long long)p0 * 256;
        for (int i = tid * 4; i < 64 * 256; i += 1024) {
            float4 v = *(const float4*)&xs[i];
            int m = i >> 8, k = i & 255;
            unsigned short* d = &As[m * APAD + k];
            d[0] = f2b(v.x); d[1] = f2b(v.y); d[2] = f2b(v.z); d[3] = f2b(v.w);
        }
    }
    __syncthreads();

    const int wv = tid >> 6;
    const int lane = tid & 63;
    const int col = lane & 15;
    const int quad = lane >> 4;
    const int nt0 = wv * 5;

    f32x4 acc[4][5];
#pragma unroll
    for (int i = 0; i < 4; ++i)
#pragma unroll
        for (int j = 0; j < 5; ++j) acc[i][j] = (f32x4){0.f, 0.f, 0.f, 0.f};

    for (int kc = 0; kc < 8; ++kc) {
        const int kb = kc * 32 + quad * 8;
        bf16x8 a[4], b[5];
#pragma unroll
        for (int mt = 0; mt < 4; ++mt)
            a[mt] = *(const bf16x8*)&As[(mt * 16 + col) * APAD + kb];
#pragma unroll
        for (int nt = 0; nt < 5; ++nt)
            b[nt] = *(const bf16x8*)&Bt[((nt0 + nt) * 16 + col) * 256 + kb];
#pragma unroll
        for (int mt = 0; mt < 4; ++mt)
#pragma unroll
            for (int nt = 0; nt < 5; ++nt)
                acc[mt][nt] = __builtin_amdgcn_mfma_f32_16x16x32_bf16(
                    a[mt], b[nt], acc[mt][nt], 0, 0, 0);
    }

    // epilogue: D row = quad*4+reg, col = col
#pragma unroll
    for (int nt = 0; nt < 5; ++nt) {
        const int n = (nt0 + nt) * 16 + col;
        if (n < 256) {
            const float bv = bi[n];
#pragma unroll
            for (int mt = 0; mt < 4; ++mt) {
                const int prow = p0 + mt * 16 + quad * 4;
#pragma unroll
                for (int rg = 0; rg < 4; ++rg)
                    xi_b[(long long)(prow + rg) * 256 + n] = f2b(acc[mt][nt][rg] + bv);
            }
        } else {
            const int d = n - 256;
            const float brd = br[d], md = mean[d], bt = beta[d];
            const float sc = gamma[d] * rsqrtf(var[d] + BN_EPS);
#pragma unroll
            for (int mt = 0; mt < 4; ++mt) {
                const int prow = p0 + mt * 16 + quad * 4;
#pragma unroll
                for (int rg = 0; rg < 4; ++rg) {
                    float v = (acc[mt][nt][rg] + brd - md) * sc + bt;
                    r_b[(long long)(prow + rg) * 64 + d] = f2b(fmaxf(v, 0.f));
                }
            }
        }
    }
}

// ---------------------------------------------------------------------------
// k2: MFMA GEMM  w[65536,144] = r[65536,64] @ Wst^T  (+bs), bf16 out.
// block = 4 waves, each wave 16 px x 144 n (9 n-tiles), K=64 (2 chunks).
// A and B frags straight from global (r rows 128B, Wst L1-resident 18 KB).
// ---------------------------------------------------------------------------
__global__ __launch_bounds__(256, 4) void k2_span(
    const unsigned short* __restrict__ r_b, const unsigned short* __restrict__ Wst,
    const float* __restrict__ bs, unsigned short* __restrict__ w_b)
{
    const int tid = threadIdx.x;
    const int wv = tid >> 6, lane = tid & 63, col = lane & 15, quad = lane >> 4;
    const int p0 = blockIdx.x * 64 + wv * 16;

    f32x4 acc[9];
#pragma unroll
    for (int i = 0; i < 9; ++i) acc[i] = (f32x4){0.f, 0.f, 0.f, 0.f};

#pragma unroll
    for (int kc = 0; kc < 2; ++kc) {
        const int kb = kc * 32 + quad * 8;
        bf16x8 a = *(const bf16x8*)&r_b[(long long)(p0 + col) * 64 + kb];
        bf16x8 b[9];
#pragma unroll
        for (int nt = 0; nt < 9; ++nt)
            b[nt] = *(const bf16x8*)&Wst[(nt * 16 + col) * 64 + kb];
#pragma unroll
        for (int nt = 0; nt < 9; ++nt)
            acc[nt] = __builtin_amdgcn_mfma_f32_16x16x32_bf16(a, b[nt], acc[nt], 0, 0, 0);
    }
#pragma unroll
    for (int nt = 0; nt < 9; ++nt) {
        const int n = nt * 16 + col;
        const float bv = bs[n];
#pragma unroll
        for (int rg = 0; rg < 4; ++rg)
            w_b[(long long)(p0 + quad * 4 + rg) * 144 + n] = f2b(acc[nt][rg] + bv);
    }
}

// ---------------------------------------------------------------------------
// k3: gather. block = 16 px (row-aligned), 256 thr; thread = (pixel p, group g),
// computes out[p][g*16 .. g*16+15].
// Key: flat idx = g*144 + f2*9 + kk spans [g*144, g*144+144) -> at most TWO
// contiguous channel runs (split at a multiple-of-16 channel), each kpos-
// uniform -> 18 aligned ds_read_b128 replace 288 scalar LDS reads.
// LDS: halo xin[3][18] rows x 264 ch (pad 8) + w tile 16x144 = 33.1 KB.
// ---------------------------------------------------------------------------
#define XROW 264
#define OFF_W (54 * XROW)           // u16 elems
#define SM3_TOTAL (54 * XROW + 16 * 144)
__global__ __launch_bounds__(256, 4) void k3_gather(
    const unsigned short* __restrict__ xi_b, const unsigned short* __restrict__ w_b,
    float* __restrict__ out)
{
    __shared__ unsigned short sm[SM3_TOTAL];
    const int tid = threadIdx.x;
    const int pp0 = blockIdx.x * 16;
    const int bb = pp0 >> 14;
    const int h  = (pp0 >> 7) & 127;
    const int w0 = pp0 & 127;

    // stage halo: 54 rows (ki in 0..2, col in 0..17) x 512 B, 16B granules
    for (int t = tid; t < 54 * 32; t += 256) {
        const int row = t >> 5, gi = t & 31;
        const int ki = row / 18, kjc = row - ki * 18;
        const int sh = h + ki - 1;
        const int sw = w0 + kjc - 1;
        int4 v = {0, 0, 0, 0};
        if ((unsigned)sh < 128u && (unsigned)sw < 128u)
            v = *(const int4*)&xi_b[(long long)((bb * 128 + sh) * 128 + sw) * 256 + gi * 8];
        *(int4*)&sm[row * XROW + gi * 8] = v;
    }
    // stage w tile: 16*144 u16 contiguous
    for (int t = tid; t < 288; t += 256)
        *(int4*)&sm[OFF_W + t * 8] = *(const int4*)&w_b[(long long)pp0 * 144 + t * 8];
    __syncthreads();

    const int g = tid & 15;
    const int p = tid >> 4;

    const int idx0 = g * 144;
    const int kp0  = idx0 >> 8;
    const int c0   = idx0 & 255;              // multiple of 16
    int len1 = 256 - c0; if (len1 > 144) len1 = 144;
    const int kp1  = kp0 + 1;
    const int base0 = ((kp0 / 3) * 18 + (kp0 % 3) + p) * XROW + c0;
    const int base1 = (kp1 <= 8) ? (((kp1 / 3) * 18 + (kp1 % 3) + p) * XROW) : 0;

    float wf[9];
#pragma unroll
    for (int kk = 0; kk < 9; ++kk)
        wf[kk] = b2f(sm[OFF_W + p * 144 + g * 9 + kk]);

    float res[16];

    // ---- half 1: e in [0,72) -> xv blocks 0..8, f2 0..7 ----
    {
        int4 xv[9];
#pragma unroll
        for (int i = 0; i < 9; ++i) {
            const int e = i * 8;
            const int addr = (e < len1) ? (base0 + e) : (base1 + (e - len1));
            xv[i] = *(const int4*)&sm[addr];
        }
#pragma unroll
        for (int f2 = 0; f2 < 8; ++f2) {
            float a = 0.f;
#pragma unroll
            for (int kk = 0; kk < 9; ++kk) {
                const int e = f2 * 9 + kk;
                const int word = ((const int*)&xv[e >> 3])[(e >> 1) & 3];
                const unsigned short u = (e & 1) ? (unsigned short)(((unsigned)word) >> 16)
                                                 : (unsigned short)(word & 0xffff);
                a += wf[kk] * b2f(u);
            }
            res[f2] = a;
        }
    }
    // ---- half 2: e in [72,144) -> xv blocks 9..17, f2 8..15 ----
    {
        int4 xv[9];
#pragma unroll
        for (int i = 9; i < 18; ++i) {
            const int e = i * 8;
            const int addr = (e < len1) ? (base0 + e) : (base1 + (e - len1));
            xv[i - 9] = *(const int4*)&sm[addr];
        }
#pragma unroll
        for (int f2 = 8; f2 < 16; ++f2) {
            float a = 0.f;
#pragma unroll
            for (int kk = 0; kk < 9; ++kk) {
                const int e = f2 * 9 + kk;
                const int i = (e >> 3) - 9;
                const int word = ((const int*)&xv[i])[(e >> 1) & 3];
                const unsigned short u = (e & 1) ? (unsigned short)(((unsigned)word) >> 16)
                                                 : (unsigned short)(word & 0xffff);
                a += wf[kk] * b2f(u);
            }
            res[f2] = a;
        }
    }

    const long long orow = ((long long)pp0 + p) * 256 + g * 16;
#pragma unroll
    for (int q = 0; q < 4; ++q) {
        float4 o = {res[q * 4 + 0], res[q * 4 + 1], res[q * 4 + 2], res[q * 4 + 3]};
        *(float4*)&out[orow + q * 4] = o;
    }
}

// ---------------------------------------------------------------------------
extern "C" void kernel_launch(void* const* d_in, const int* in_sizes, int n_in,
                              void* d_out, int out_size, void* d_ws, size_t ws_size,
                              hipStream_t stream) {
    const float* x     = (const float*)d_in[0];
    const float* Wr    = (const float*)d_in[1];
    const float* br    = (const float*)d_in[2];
    const float* gamma = (const float*)d_in[3];
    const float* beta  = (const float*)d_in[4];
    const float* mean  = (const float*)d_in[5];
    const float* var   = (const float*)d_in[6];
    const float* Ws    = (const float*)d_in[7];
    const float* bs    = (const float*)d_in[8];
    const float* Wi    = (const float*)d_in[9];
    const float* bi    = (const float*)d_in[10];
    float* out = (float*)d_out;

    // workspace layout (bytes, all 16B-aligned)
    unsigned char* ws = (unsigned char*)d_ws;
    unsigned short* xi_b = (unsigned short*)(ws + 0);            // 65536*256*2 = 33,554,432
    unsigned short* r_b  = (unsigned short*)(ws + 33554432);     // 65536*64*2  =  8,388,608
    unsigned short* w_b  = (unsigned short*)(ws + 41943040);     // 65536*144*2 = 18,874,368
    unsigned short* Bt   = (unsigned short*)(ws + 60817408);     // 320*256*2   =    163,840
    unsigned short* Wst  = (unsigned short*)(ws + 60981248);     // 144*64*2    =     18,432

    k_prep<<<dim3((320 * 256 + 144 * 64 + 255) / 256), dim3(256), 0, stream>>>(
        Wi, Wr, Ws, Bt, Wst);
    k1_gemm<<<dim3(NPIX / 64), dim3(256), 0, stream>>>(
        x, Bt, bi, br, gamma, beta, mean, var, xi_b, r_b);
    k2_span<<<dim3(NPIX / 64), dim3(256), 0, stream>>>(r_b, Wst, bs, w_b);
    k3_gather<<<dim3(NPIX / 16), dim3(256), 0, stream>>>(xi_b, w_b, out);
}